// Round 6
// baseline (410.892 us; speedup 1.0000x reference)
//
#include <hip/hip_runtime.h>

// IntersectionGNN: out = L2(L1(x)) with L(x) = relu([max_nbr(x) | x] @ W^T + b)
// B=4, N=50000, D=8, F=128, K=2F=256.
//
// Round 6 design (delta vs round 5):
//  - TILE_N 16 -> 8: LDS 32->16KB, M=32 rows. Blocks/CU cap 5 -> 10 (LDS), and
//    VGPR<=64 via __launch_bounds__(256,8) -> up to 8 waves/SIMD. Round-5 counters
//    showed occ pinned at 37% with all pipes <45% (latency-bound): this doubles+
//    resident gather waves at identical traffic.
//  - adj indices preloaded per wave and forced scalar via readfirstlane: gathers
//    become saddr loads (SGPR base + shared lane*16 voffset) — kills the
//    adj->gather dependency stall and per-gather VALU address math.
//  - Everything else per round 5: (N,B,F) f16 layout (1KB/node line serves all
//    4 batches), f16 hi/lo W split GEMM (err ~5e-4 << 0.0156 resid), XOR-swizzled
//    LDS, contiguous interT writes, nontemporal final f32 stores.
//  - d_ws: [xT 51.2MB][interT 51.2MB][W splits 256KB].

#define N_NODES 50000
#define N_BATCH 4
#define DEG 8
#define FDIM 128
#define K2 256
#define TILE_N 8  // nodes per block -> M = 32 rows (8 nodes x 4 batches)

typedef _Float16 f16x8 __attribute__((ext_vector_type(8)));
typedef _Float16 f16x4 __attribute__((ext_vector_type(4)));
typedef float f32x4 __attribute__((ext_vector_type(4)));

__global__ void split_w_kernel(const float* __restrict__ W1, const float* __restrict__ W2,
                               _Float16* __restrict__ w1h, _Float16* __restrict__ w1l,
                               _Float16* __restrict__ w2h, _Float16* __restrict__ w2l) {
  const int i = blockIdx.x * 256 + threadIdx.x;  // 128 blocks: exactly 128*256 = 32768
  {
    const float a = W1[i];
    const _Float16 h = (_Float16)a;
    w1h[i] = h;
    w1l[i] = (_Float16)(a - (float)h);
  }
  {
    const float a = W2[i];
    const _Float16 h = (_Float16)a;
    w2h[i] = h;
    w2l[i] = (_Float16)(a - (float)h);
  }
}

// (B,N,F) f32 -> (N,B,F) f16. One wave per node: lane = (b = l>>4, 8-col chunk).
__global__ void transpose_x_kernel(const float* __restrict__ x, _Float16* __restrict__ xT) {
  const int wv = threadIdx.x >> 6, l = threadIdx.x & 63;
  const int n = blockIdx.x * 4 + wv;  // grid 12500: exactly 50000 nodes
  const int b = l >> 4;
  const int c8 = (l & 15) * 8;
  const float* src = x + ((size_t)b * N_NODES + n) * FDIM + c8;
  const f32x4 v0 = *(const f32x4*)src;
  const f32x4 v1 = *(const f32x4*)(src + 4);
  f16x8 h;
  #pragma unroll
  for (int j = 0; j < 4; ++j) h[j] = (_Float16)v0[j];
  #pragma unroll
  for (int j = 0; j < 4; ++j) h[4 + j] = (_Float16)v1[j];
  *(f16x8*)(xT + ((size_t)n * N_BATCH + b) * FDIM + c8) = h;
}

static __device__ inline f16x8 vmax8(f16x8 a, f16x8 b) {
  f16x8 r;
  #pragma unroll
  for (int j = 0; j < 8; ++j) r[j] = a[j] > b[j] ? a[j] : b[j];
  return r;
}

template <bool OUT_F32>
__global__ __launch_bounds__(256, 8)
void gnn_layer_kernel(const _Float16* __restrict__ xT, const int* __restrict__ adj,
                      const _Float16* __restrict__ Wh, const _Float16* __restrict__ Wl,
                      const float* __restrict__ bias, void* __restrict__ out_) {
  __shared__ unsigned char lds[16384];  // cc f16: 32 rows x 512B, XOR-swizzled

  const int tid = (int)threadIdx.x;
  const int n0  = (int)blockIdx.x * TILE_N;  // grid 6250: exact

  const int l   = tid & 63;
  const int wv  = tid >> 6;   // wave 0..3
  const int col = l & 15;
  const int kg  = l >> 4;
  const int o0  = wv * 32;    // wave's output cols [o0, o0+32)

  // ---- gather-max (all-batch 1KB rows) + concat into LDS ----
  const int bb = l >> 4;         // batch
  const int c8 = (l & 15) * 8;   // f16 col base
  const size_t laneoff = (size_t)bb * FDIM + c8;

  // Preload this wave's 2 adj rows; force indices scalar (wave-uniform) so the
  // 9 gathers per node are saddr loads with one shared voffset.
  const int nbase = n0 + wv * 2;
  int idx[2][8];
  {
    const int4* ap4 = (const int4*)(adj + nbase * DEG);  // 32B-aligned
    const int4 q0 = ap4[0], q1 = ap4[1], q2 = ap4[2], q3 = ap4[3];
    idx[0][0] = __builtin_amdgcn_readfirstlane(q0.x);
    idx[0][1] = __builtin_amdgcn_readfirstlane(q0.y);
    idx[0][2] = __builtin_amdgcn_readfirstlane(q0.z);
    idx[0][3] = __builtin_amdgcn_readfirstlane(q0.w);
    idx[0][4] = __builtin_amdgcn_readfirstlane(q1.x);
    idx[0][5] = __builtin_amdgcn_readfirstlane(q1.y);
    idx[0][6] = __builtin_amdgcn_readfirstlane(q1.z);
    idx[0][7] = __builtin_amdgcn_readfirstlane(q1.w);
    idx[1][0] = __builtin_amdgcn_readfirstlane(q2.x);
    idx[1][1] = __builtin_amdgcn_readfirstlane(q2.y);
    idx[1][2] = __builtin_amdgcn_readfirstlane(q2.z);
    idx[1][3] = __builtin_amdgcn_readfirstlane(q2.w);
    idx[1][4] = __builtin_amdgcn_readfirstlane(q3.x);
    idx[1][5] = __builtin_amdgcn_readfirstlane(q3.y);
    idx[1][6] = __builtin_amdgcn_readfirstlane(q3.z);
    idx[1][7] = __builtin_amdgcn_readfirstlane(q3.w);
  }

  #pragma unroll
  for (int i = 0; i < 2; ++i) {
    const int ng = nbase + i;
    f16x8 v[DEG];
    #pragma unroll
    for (int d = 0; d < DEG; ++d)
      v[d] = *(const f16x8*)(xT + (size_t)idx[i][d] * (N_BATCH * FDIM) + laneoff);
    const f16x8 xv = *(const f16x8*)(xT + (size_t)ng * (N_BATCH * FDIM) + laneoff);
    const f16x8 agg = vmax8(vmax8(vmax8(v[0], v[1]), vmax8(v[2], v[3])),
                            vmax8(vmax8(v[4], v[5]), vmax8(v[6], v[7])));
    const int r   = (wv * 2 + i) * N_BATCH + bb;   // LDS/output row 0..31
    const int swz = (r & 7) << 4;
    *(f16x8*)(lds + r * 512 + ((c8 * 2) ^ swz))         = agg;  // k [0,128)
    *(f16x8*)(lds + r * 512 + (256 + ((c8 * 2) ^ swz))) = xv;   // k [128,256)
  }

  __syncthreads();

  // ---- MFMA: D[32x128] = cc[32x256] . W^T, 16x16x32 f16, W hi/lo 2-term ----
  f32x4 acc[2][2] = {};
  #pragma unroll
  for (int h2 = 0; h2 < 2; ++h2) {
    #pragma unroll
    for (int kt = 0; kt < 4; ++kt) {
      const int k = h2 * 128 + kt * 32 + kg * 8;
      const f16x8 Bh0 = *(const f16x8*)(Wh + (o0 + col) * K2 + k);
      const f16x8 Bh1 = *(const f16x8*)(Wh + (o0 + 16 + col) * K2 + k);
      const f16x8 Bl0 = *(const f16x8*)(Wl + (o0 + col) * K2 + k);
      const f16x8 Bl1 = *(const f16x8*)(Wl + (o0 + 16 + col) * K2 + k);
      f16x8 Ah[2];
      #pragma unroll
      for (int mf = 0; mf < 2; ++mf) {
        const int row = mf * 16 + col;
        const int kb  = k * 2;  // byte col; k>=128 lives at 256+((kb&255)^swz)
        Ah[mf] = *(const f16x8*)(lds + row * 512 +
                                 ((kb & 256) | ((kb & 255) ^ ((row & 7) << 4))));
      }
      #pragma unroll
      for (int mf = 0; mf < 2; ++mf) {
        acc[mf][0] = __builtin_amdgcn_mfma_f32_16x16x32_f16(Ah[mf], Bh0, acc[mf][0], 0, 0, 0);
        acc[mf][0] = __builtin_amdgcn_mfma_f32_16x16x32_f16(Ah[mf], Bl0, acc[mf][0], 0, 0, 0);
        acc[mf][1] = __builtin_amdgcn_mfma_f32_16x16x32_f16(Ah[mf], Bh1, acc[mf][1], 0, 0, 0);
        acc[mf][1] = __builtin_amdgcn_mfma_f32_16x16x32_f16(Ah[mf], Bl1, acc[mf][1], 0, 0, 0);
      }
    }
  }

  // ---- epilogue: bias + relu + store (C/D: col=lane&15, row=(lane>>4)*4+j) ----
  const float bv0 = bias[o0 + col];
  const float bv1 = bias[o0 + 16 + col];
  #pragma unroll
  for (int mf = 0; mf < 2; ++mf) {
    #pragma unroll
    for (int j = 0; j < 4; ++j) {
      const int r = mf * 16 + kg * 4 + j;  // block row = (node nl=r>>2, batch b=r&3)
      const float r0 = fmaxf(acc[mf][0][j] + bv0, 0.f);
      const float r1 = fmaxf(acc[mf][1][j] + bv1, 0.f);
      if (OUT_F32) {
        const int b = r & 3, n = n0 + (r >> 2);
        float* orow = (float*)out_ + ((size_t)b * N_NODES + n) * FDIM;
        __builtin_nontemporal_store(r0, &orow[o0 + col]);
        __builtin_nontemporal_store(r1, &orow[o0 + 16 + col]);
      } else {
        // inter_T row index = (n0 + (r>>2))*4 + (r&3) = n0*4 + r  (contiguous!)
        _Float16* orow = (_Float16*)out_ + ((size_t)n0 * N_BATCH + r) * FDIM;
        orow[o0 + col]      = (_Float16)r0;
        orow[o0 + 16 + col] = (_Float16)r1;
      }
    }
  }
}

extern "C" void kernel_launch(void* const* d_in, const int* in_sizes, int n_in,
                              void* d_out, int out_size, void* d_ws, size_t ws_size,
                              hipStream_t stream) {
  const float* x  = (const float*)d_in[0];
  const int* adj  = (const int*)d_in[1];
  const float* W1 = (const float*)d_in[2];
  const float* b1 = (const float*)d_in[3];
  const float* W2 = (const float*)d_in[4];
  const float* b2 = (const float*)d_in[5];
  float* out      = (float*)d_out;

  char* ws = (char*)d_ws;
  const size_t nElem = (size_t)N_BATCH * N_NODES * FDIM;  // 25.6M
  _Float16* xT    = (_Float16*)ws;  // (N,B,F) f16, 51.2 MB
  _Float16* inter = xT + nElem;     // (N,B,F) f16, 51.2 MB
  _Float16* w1h   = inter + nElem;
  _Float16* w1l   = w1h + 32768;
  _Float16* w2h   = w1l + 32768;
  _Float16* w2l   = w2h + 32768;

  split_w_kernel<<<128, 256, 0, stream>>>(W1, W2, w1h, w1l, w2h, w2l);
  transpose_x_kernel<<<12500, 256, 0, stream>>>(x, xT);

  const int grid = N_NODES / TILE_N;  // 6250
  gnn_layer_kernel<false><<<grid, 256, 0, stream>>>(xT, adj, w1h, w1l, b1, inter);
  gnn_layer_kernel<true><<<grid, 256, 0, stream>>>(inter, adj, w2h, w2l, b2, out);
}

// Round 7
// 350.418 us; speedup vs baseline: 1.1726x; 1.1726x over previous
//
#include <hip/hip_runtime.h>

// IntersectionGNN: out = L2(L1(x)) with L(x) = relu([max_nbr(x) | x] @ W^T + b)
// B=4, N=50000, D=8, F=128, K=2F=256.
//
// Round 7 design (= round-5 base + deeper gather MLP; round-6 taught us
// occupancy is NOT the constraint, per-wave loads-in-flight is):
//  - TILE_N=16 (M=64 rows), LDS 32KB, 4 waves — the best-known config (97us/layer).
//  - __launch_bounds__(256,4): VGPR budget ~128 so the gather can hold 18
//    f16x8 loads in flight (round 5: 48 VGPR => ~9 in flight; round 6's
//    bounds(256,8) => 32 VGPR serialized loads, 2.1 TB/s regression).
//  - Gather: wave owns 4 nodes; adj rows preloaded once and scalarized via
//    readfirstlane (saddr loads, no per-load VALU); 2 passes x 2 nodes with
//    all 18 row-loads issued before the max trees.
//  - (N,B,F) f16 layout: one 1KB line per node serves all 4 batches.
//  - GEMM: A=f16 cc, W f16 hi/lo -> acc = Ah*Bh + Ah*Bl (err ~5e-4 << 0.0156 resid).
//  - XOR-swizzled LDS ((row&7)<<4); contiguous interT writes; nt f32 final stores.
//  - d_ws: [xT 51.2MB][interT 51.2MB][W splits 256KB].

#define N_NODES 50000
#define N_BATCH 4
#define DEG 8
#define FDIM 128
#define K2 256
#define TILE_N 16  // nodes per block -> M = 64 rows (16 nodes x 4 batches)

typedef _Float16 f16x8 __attribute__((ext_vector_type(8)));
typedef _Float16 f16x4 __attribute__((ext_vector_type(4)));
typedef float f32x4 __attribute__((ext_vector_type(4)));

__global__ void split_w_kernel(const float* __restrict__ W1, const float* __restrict__ W2,
                               _Float16* __restrict__ w1h, _Float16* __restrict__ w1l,
                               _Float16* __restrict__ w2h, _Float16* __restrict__ w2l) {
  const int i = blockIdx.x * 256 + threadIdx.x;  // 128 blocks: exactly 128*256 = 32768
  {
    const float a = W1[i];
    const _Float16 h = (_Float16)a;
    w1h[i] = h;
    w1l[i] = (_Float16)(a - (float)h);
  }
  {
    const float a = W2[i];
    const _Float16 h = (_Float16)a;
    w2h[i] = h;
    w2l[i] = (_Float16)(a - (float)h);
  }
}

// (B,N,F) f32 -> (N,B,F) f16. One wave per node: lane = (b = l>>4, 8-col chunk).
__global__ void transpose_x_kernel(const float* __restrict__ x, _Float16* __restrict__ xT) {
  const int wv = threadIdx.x >> 6, l = threadIdx.x & 63;
  const int n = blockIdx.x * 4 + wv;  // grid 12500: exactly 50000 nodes
  const int b = l >> 4;
  const int c8 = (l & 15) * 8;
  const float* src = x + ((size_t)b * N_NODES + n) * FDIM + c8;
  const f32x4 v0 = *(const f32x4*)src;
  const f32x4 v1 = *(const f32x4*)(src + 4);
  f16x8 h;
  #pragma unroll
  for (int j = 0; j < 4; ++j) h[j] = (_Float16)v0[j];
  #pragma unroll
  for (int j = 0; j < 4; ++j) h[4 + j] = (_Float16)v1[j];
  *(f16x8*)(xT + ((size_t)n * N_BATCH + b) * FDIM + c8) = h;
}

static __device__ inline f16x8 vmax8(f16x8 a, f16x8 b) {
  f16x8 r;
  #pragma unroll
  for (int j = 0; j < 8; ++j) r[j] = a[j] > b[j] ? a[j] : b[j];
  return r;
}

template <bool OUT_F32>
__global__ __launch_bounds__(256, 4)
void gnn_layer_kernel(const _Float16* __restrict__ xT, const int* __restrict__ adj,
                      const _Float16* __restrict__ Wh, const _Float16* __restrict__ Wl,
                      const float* __restrict__ bias, void* __restrict__ out_) {
  __shared__ unsigned char lds[32768];  // cc f16: 64 rows x 512B, XOR-swizzled

  const int tid = (int)threadIdx.x;
  const int n0  = (int)blockIdx.x * TILE_N;  // grid 3125: exact

  const int l   = tid & 63;
  const int wv  = tid >> 6;   // wave 0..3
  const int col = l & 15;
  const int kg  = l >> 4;
  const int o0  = wv * 32;    // wave's output cols [o0, o0+32)

  // ---- gather-max (all-batch 1KB rows) + concat into LDS ----
  const int bb = l >> 4;         // batch
  const int c8 = (l & 15) * 8;   // f16 col base
  const size_t laneoff = (size_t)bb * FDIM + c8;

  // Wave owns nodes nbase..nbase+3. Preload the 4 adj rows (8 ints each) and
  // scalarize via readfirstlane -> gathers become saddr-form loads.
  const int nbase = n0 + wv * 4;
  int idx[4][8];
  #pragma unroll
  for (int i = 0; i < 4; ++i) {
    const int4* ap4 = (const int4*)(adj + (nbase + i) * DEG);  // 32B-aligned
    const int4 q0 = ap4[0], q1 = ap4[1];
    idx[i][0] = __builtin_amdgcn_readfirstlane(q0.x);
    idx[i][1] = __builtin_amdgcn_readfirstlane(q0.y);
    idx[i][2] = __builtin_amdgcn_readfirstlane(q0.z);
    idx[i][3] = __builtin_amdgcn_readfirstlane(q0.w);
    idx[i][4] = __builtin_amdgcn_readfirstlane(q1.x);
    idx[i][5] = __builtin_amdgcn_readfirstlane(q1.y);
    idx[i][6] = __builtin_amdgcn_readfirstlane(q1.z);
    idx[i][7] = __builtin_amdgcn_readfirstlane(q1.w);
  }

  // 2 passes x 2 nodes: issue all 18 row-loads (2x8 nbrs + 2 self) before the
  // max trees so they are simultaneously in flight (~72 VGPRs of payload).
  #pragma unroll
  for (int p = 0; p < 2; ++p) {
    const int na = nbase + p * 2;      // node A
    const int nbn = na + 1;            // node B
    f16x8 va[DEG], vb[DEG];
    #pragma unroll
    for (int d = 0; d < DEG; ++d)
      va[d] = *(const f16x8*)(xT + (size_t)idx[p * 2][d] * (N_BATCH * FDIM) + laneoff);
    #pragma unroll
    for (int d = 0; d < DEG; ++d)
      vb[d] = *(const f16x8*)(xT + (size_t)idx[p * 2 + 1][d] * (N_BATCH * FDIM) + laneoff);
    const f16x8 xa = *(const f16x8*)(xT + (size_t)na * (N_BATCH * FDIM) + laneoff);
    const f16x8 xb = *(const f16x8*)(xT + (size_t)nbn * (N_BATCH * FDIM) + laneoff);

    const f16x8 agga = vmax8(vmax8(vmax8(va[0], va[1]), vmax8(va[2], va[3])),
                             vmax8(vmax8(va[4], va[5]), vmax8(va[6], va[7])));
    const f16x8 aggb = vmax8(vmax8(vmax8(vb[0], vb[1]), vmax8(vb[2], vb[3])),
                             vmax8(vmax8(vb[4], vb[5]), vmax8(vb[6], vb[7])));

    const int ra  = (wv * 4 + p * 2) * N_BATCH + bb;   // LDS row for node A
    const int rb  = ra + N_BATCH;                      // LDS row for node B
    const int swa = (ra & 7) << 4;
    const int swb = (rb & 7) << 4;
    *(f16x8*)(lds + ra * 512 + ((c8 * 2) ^ swa))         = agga;  // k [0,128)
    *(f16x8*)(lds + ra * 512 + (256 + ((c8 * 2) ^ swa))) = xa;    // k [128,256)
    *(f16x8*)(lds + rb * 512 + ((c8 * 2) ^ swb))         = aggb;
    *(f16x8*)(lds + rb * 512 + (256 + ((c8 * 2) ^ swb))) = xb;
  }

  __syncthreads();

  // ---- MFMA: D[64x128] = cc[64x256] . W^T, 16x16x32 f16, W hi/lo 2-term ----
  f32x4 acc[4][2] = {};
  #pragma unroll
  for (int h2 = 0; h2 < 2; ++h2) {
    #pragma unroll
    for (int kt = 0; kt < 4; ++kt) {
      const int k = h2 * 128 + kt * 32 + kg * 8;
      const f16x8 Bh0 = *(const f16x8*)(Wh + (o0 + col) * K2 + k);
      const f16x8 Bh1 = *(const f16x8*)(Wh + (o0 + 16 + col) * K2 + k);
      const f16x8 Bl0 = *(const f16x8*)(Wl + (o0 + col) * K2 + k);
      const f16x8 Bl1 = *(const f16x8*)(Wl + (o0 + 16 + col) * K2 + k);
      f16x8 Ah[4];
      #pragma unroll
      for (int mf = 0; mf < 4; ++mf) {
        const int row = mf * 16 + col;
        const int kb  = k * 2;  // byte col; k>=128 lives at 256+((kb&255)^swz)
        Ah[mf] = *(const f16x8*)(lds + row * 512 +
                                 ((kb & 256) | ((kb & 255) ^ ((row & 7) << 4))));
      }
      #pragma unroll
      for (int mf = 0; mf < 4; ++mf) {
        acc[mf][0] = __builtin_amdgcn_mfma_f32_16x16x32_f16(Ah[mf], Bh0, acc[mf][0], 0, 0, 0);
        acc[mf][0] = __builtin_amdgcn_mfma_f32_16x16x32_f16(Ah[mf], Bl0, acc[mf][0], 0, 0, 0);
        acc[mf][1] = __builtin_amdgcn_mfma_f32_16x16x32_f16(Ah[mf], Bh1, acc[mf][1], 0, 0, 0);
        acc[mf][1] = __builtin_amdgcn_mfma_f32_16x16x32_f16(Ah[mf], Bl1, acc[mf][1], 0, 0, 0);
      }
    }
  }

  // ---- epilogue: bias + relu + store (C/D: col=lane&15, row=(lane>>4)*4+j) ----
  const float bv0 = bias[o0 + col];
  const float bv1 = bias[o0 + 16 + col];
  #pragma unroll
  for (int mf = 0; mf < 4; ++mf) {
    #pragma unroll
    for (int j = 0; j < 4; ++j) {
      const int r = mf * 16 + kg * 4 + j;  // block row = (node nl=r>>2, batch b=r&3)
      const float r0 = fmaxf(acc[mf][0][j] + bv0, 0.f);
      const float r1 = fmaxf(acc[mf][1][j] + bv1, 0.f);
      if (OUT_F32) {
        const int b = r & 3, n = n0 + (r >> 2);
        float* orow = (float*)out_ + ((size_t)b * N_NODES + n) * FDIM;
        __builtin_nontemporal_store(r0, &orow[o0 + col]);
        __builtin_nontemporal_store(r1, &orow[o0 + 16 + col]);
      } else {
        // inter_T row index = (n0 + (r>>2))*4 + (r&3) = n0*4 + r  (contiguous!)
        _Float16* orow = (_Float16*)out_ + ((size_t)n0 * N_BATCH + r) * FDIM;
        orow[o0 + col]      = (_Float16)r0;
        orow[o0 + 16 + col] = (_Float16)r1;
      }
    }
  }
}

extern "C" void kernel_launch(void* const* d_in, const int* in_sizes, int n_in,
                              void* d_out, int out_size, void* d_ws, size_t ws_size,
                              hipStream_t stream) {
  const float* x  = (const float*)d_in[0];
  const int* adj  = (const int*)d_in[1];
  const float* W1 = (const float*)d_in[2];
  const float* b1 = (const float*)d_in[3];
  const float* W2 = (const float*)d_in[4];
  const float* b2 = (const float*)d_in[5];
  float* out      = (float*)d_out;

  char* ws = (char*)d_ws;
  const size_t nElem = (size_t)N_BATCH * N_NODES * FDIM;  // 25.6M
  _Float16* xT    = (_Float16*)ws;  // (N,B,F) f16, 51.2 MB
  _Float16* inter = xT + nElem;     // (N,B,F) f16, 51.2 MB
  _Float16* w1h   = inter + nElem;
  _Float16* w1l   = w1h + 32768;
  _Float16* w2h   = w1l + 32768;
  _Float16* w2l   = w2h + 32768;

  split_w_kernel<<<128, 256, 0, stream>>>(W1, W2, w1h, w1l, w2h, w2l);
  transpose_x_kernel<<<12500, 256, 0, stream>>>(x, xT);

  const int grid = N_NODES / TILE_N;  // 3125
  gnn_layer_kernel<false><<<grid, 256, 0, stream>>>(xT, adj, w1h, w1l, b1, inter);
  gnn_layer_kernel<true><<<grid, 256, 0, stream>>>(inter, adj, w2h, w2l, b2, out);
}